// Round 1
// baseline (223.460 us; speedup 1.0000x reference)
//
#include <hip/hip_runtime.h>
#include <stdint.h>

// ThresholdDecision: out[b] = 1 iff row b of x[:, :, 2] has 4 consecutive
// values > 0.5 within positions [1, 4094] (window starts 1..4091), per the
// reference's shifted-cumsum construction.
//
// Strategy: one wave per row. Lane l reads position chunk*64+l of channel 2,
// __ballot builds a 64-bit mask per chunk; run-of-4 = m & m>>1 & m>>2 & m>>3,
// with a 3-bit carry for runs crossing chunk boundaries. Early exit: with
// uniform random input, P(run start) = 1/16, so ~99.95% of rows resolve in
// the first 256 positions -> we scan 4 chunks (256 pos) per iteration with
// independent loads for ILP, then break wave-uniformly.

#define L_SEQ 4096
#define ROW_FLOATS (L_SEQ * 3)

__global__ __launch_bounds__(256) void threshold_decision_kernel(
    const float* __restrict__ x, int* __restrict__ out, int B)
{
    const int lane = threadIdx.x & 63;
    const int waveInBlock = threadIdx.x >> 6;
    const int row = blockIdx.x * 4 + waveInBlock;
    if (row >= B) return;

    // pointer to channel 2 of this row; position p lives at xp[p*3]
    const float* xp = x + (size_t)row * ROW_FLOATS + 2;

    unsigned long long carry = 0;  // top 3 bits of previous chunk, in bits 0..2
    int found = 0;

    for (int cBase = 0; cBase < 64; cBase += 4) {
        // 4 independent strided loads (4 chunks of 64 positions)
        float v0 = xp[(size_t)((cBase + 0) * 64 + lane) * 3];
        float v1 = xp[(size_t)((cBase + 1) * 64 + lane) * 3];
        float v2 = xp[(size_t)((cBase + 2) * 64 + lane) * 3];
        float v3 = xp[(size_t)((cBase + 3) * 64 + lane) * 3];

        unsigned long long m[4];
        m[0] = __ballot(v0 > 0.5f);
        m[1] = __ballot(v1 > 0.5f);
        m[2] = __ballot(v2 > 0.5f);
        m[3] = __ballot(v3 > 0.5f);

        // exclude position 0 (chunk 0, bit 0) and position 4095 (chunk 63, bit 63)
        if (cBase == 0)  m[0] &= ~1ull;
        if (cBase == 60) m[3] &= ~(1ull << 63);

        #pragma unroll
        for (int k = 0; k < 4; k++) {
            unsigned long long mm = m[k];
            // run of >=4 fully inside this chunk
            unsigned long long r = mm & (mm >> 1) & (mm >> 2) & (mm >> 3);
            // run of 4 crossing the previous chunk boundary:
            // 6-bit window = [prev bits 61..63 | this bits 0..2]
            unsigned long long comb = carry | ((mm & 7ull) << 3);
            unsigned long long t = comb & (comb >> 1) & (comb >> 2) & (comb >> 3);
            found |= (r != 0) | (t != 0);
            carry = mm >> 61;
        }
        if (found) break;  // wave-uniform (ballot result identical on all lanes)
    }

    if (lane == 0) out[row] = found ? 1 : 0;
}

extern "C" void kernel_launch(void* const* d_in, const int* in_sizes, int n_in,
                              void* d_out, int out_size, void* d_ws, size_t ws_size,
                              hipStream_t stream) {
    const float* x = (const float*)d_in[0];
    int* out = (int*)d_out;
    const int B = out_size;  // 4096
    dim3 grid((B + 3) / 4);
    threshold_decision_kernel<<<grid, 256, 0, stream>>>(x, out, B);
}

// Round 2
// 223.342 us; speedup vs baseline: 1.0005x; 1.0005x over previous
//
#include <hip/hip_runtime.h>
#include <stdint.h>

// ThresholdDecision: out[b] = 1 iff row b of x[:, :, 2] (threshold 0.5) has a
// run of 4 consecutive above-threshold values with window start s in [1,4091]
// — equivalently: clear position 0 and position 4095, then find any 4-run.
//
// One wave per row. Round = 256 positions: lane l loads 3 contiguous float4
// (positions 4l..4l+3, channels interleaved; ch2 = a.z, b.y, c.x, c.w) ->
// fully coalesced dwordx4, 3 KB/wave/round. Per-lane 4-bit mask; runs checked
// against neighbor lane's low 3 bits (shfl_down) and across round boundaries
// via a 3-bit carry. Early exit is wave-uniform (ballot/broadcast-derived).
// Expected rounds/row ~1.0 (P(no 4-run in 256 uniform positions) ~ 5e-4).

#define L_SEQ 4096
#define ROW_FLOATS (L_SEQ * 3)

__global__ __launch_bounds__(256) void threshold_decision_kernel(
    const float* __restrict__ x, int* __restrict__ out, int B)
{
    const int lane = threadIdx.x & 63;
    const int waveInBlock = threadIdx.x >> 6;
    const int row = blockIdx.x * 4 + waveInBlock;
    if (row >= B) return;

    // row base: row*12288 floats -> 49152 B, 16B-aligned
    const float4* xp = (const float4*)(x + (size_t)row * ROW_FLOATS);

    unsigned carry = 0;  // bits 0..2 = previous round's positions 253..255
    int found = 0;

    for (int rnd = 0; rnd < 16; ++rnd) {
        // lane l of round rnd covers positions rnd*256 + 4l .. +3
        // float4 index: (rnd*256 + 4l)*3/4 = rnd*192 + 3l
        const float4* p = xp + rnd * 192 + lane * 3;
        float4 a = p[0];
        float4 b = p[1];
        float4 c = p[2];

        unsigned own = (a.z > 0.5f ? 1u : 0u)
                     | (b.y > 0.5f ? 2u : 0u)
                     | (c.x > 0.5f ? 4u : 0u)
                     | (c.w > 0.5f ? 8u : 0u);

        // exclusions: position 0 (rnd 0, lane 0, bit 0) and
        //             position 4095 (rnd 15, lane 63, bit 3)
        if (rnd == 0  && lane == 0)  own &= ~1u;
        if (rnd == 15 && lane == 63) own &= ~8u;

        // neighbor lane's low 3 bits -> 7-bit window; detects runs starting
        // at any of this lane's 4 positions (except across round boundary)
        unsigned nxt = (unsigned)__shfl_down((int)own, 1);
        if (lane == 63) nxt = 0;
        unsigned w  = own | ((nxt & 7u) << 4);
        unsigned r4 = w & (w >> 1) & (w >> 2) & (w >> 3);
        int local = (r4 & 0xFu) != 0;

        unsigned long long bal = __ballot(local);

        // round-boundary runs: prev round's last 3 positions + this round's
        // first 3 positions (lane 0 bits 0..2)
        unsigned first = (unsigned)__shfl((int)own, 0);
        unsigned last  = (unsigned)__shfl((int)own, 63);
        unsigned comb  = carry | ((first & 7u) << 3);  // 6-bit window
        unsigned t     = comb & (comb >> 1) & (comb >> 2) & (comb >> 3);

        found = (bal != 0) | (t != 0);   // uniform across the wave
        carry = (last >> 1) & 7u;
        if (found) break;                // wave-uniform break
    }

    if (lane == 0) out[row] = found;
}

extern "C" void kernel_launch(void* const* d_in, const int* in_sizes, int n_in,
                              void* d_out, int out_size, void* d_ws, size_t ws_size,
                              hipStream_t stream) {
    const float* x = (const float*)d_in[0];
    int* out = (int*)d_out;
    const int B = out_size;  // 4096
    dim3 grid((B + 3) / 4);
    threshold_decision_kernel<<<grid, 256, 0, stream>>>(x, out, B);
}